// Round 1
// baseline (212.528 us; speedup 1.0000x reference)
//
#include <hip/hip_runtime.h>
#include <hip/hip_bf16.h>

typedef __attribute__((ext_vector_type(8))) short s16x8;
typedef __attribute__((ext_vector_type(4))) float f32x4;
typedef unsigned short u16;

#define NB 16
#define NK 256
#define APP 768
#define DKK 96
#define NR 8

__device__ __forceinline__ u16 f2bf(float f) {
  union { float f; unsigned int u; } v; v.f = f;
  unsigned int x = v.u;
  x += 0x7fffu + ((x >> 16) & 1u);
  return (u16)(x >> 16);
}
__device__ __forceinline__ float bf2f(u16 h) {
  union { unsigned int u; float f; } v; v.u = ((unsigned int)h) << 16;
  return v.f;
}

// ---------------------------------------------------------------------------
// Kernel 1: projections.  C[m, c] = f_a[m,:] . Wcat[c,:] + bcat[c]
// m = b*256+t (4096 rows), c = arr*768 + (r*96+k) (2304 cols), inner = 768.
// Output scattered to wk/wq/wv as bf16 [r][b][t][k].
// 128x128 tile, 4 waves (each 64x64 = 4x4 frags of 16x16x32 bf16 MFMA).
// ---------------------------------------------------------------------------
__global__ __launch_bounds__(256) void proj_kernel(
    const float* __restrict__ fa,
    const float* __restrict__ WKw, const float* __restrict__ WKb,
    const float* __restrict__ WQw, const float* __restrict__ WQb,
    const float* __restrict__ WVw, const float* __restrict__ WVb,
    u16* __restrict__ wk, u16* __restrict__ wq, u16* __restrict__ wv)
{
  __shared__ short At[128][56];   // rows padded 32->56 (112B, 16B-aligned, 2-way banks)
  __shared__ short Bt[128][56];
  const int t = threadIdx.x;
  const int lane = t & 63;
  const int w = t >> 6;
  const int c = lane & 15, g = lane >> 4;
  const int wr = w >> 1, wc = w & 1;
  const int m0 = blockIdx.x * 128;
  const int c0 = blockIdx.y * 128;
  const int arr = c0 / APP;
  const float* Wp = arr == 0 ? WKw : (arr == 1 ? WQw : WVw);
  const float* bp = arr == 0 ? WKb : (arr == 1 ? WQb : WVb);
  u16* outp = arr == 0 ? wk : (arr == 1 ? wq : wv);
  const int cw0 = c0 % APP;

  const int srow = t >> 1, scol = (t & 1) * 16;
  f32x4 acc[4][4] = {};

  for (int k0 = 0; k0 < APP; k0 += 32) {
    __syncthreads();
    {
      const float* s = fa + (size_t)(m0 + srow) * APP + k0 + scol;
      float4 v0 = *(const float4*)(s);
      float4 v1 = *(const float4*)(s + 4);
      float4 v2 = *(const float4*)(s + 8);
      float4 v3 = *(const float4*)(s + 12);
      s16x8 o0 = {(short)f2bf(v0.x),(short)f2bf(v0.y),(short)f2bf(v0.z),(short)f2bf(v0.w),
                  (short)f2bf(v1.x),(short)f2bf(v1.y),(short)f2bf(v1.z),(short)f2bf(v1.w)};
      s16x8 o1 = {(short)f2bf(v2.x),(short)f2bf(v2.y),(short)f2bf(v2.z),(short)f2bf(v2.w),
                  (short)f2bf(v3.x),(short)f2bf(v3.y),(short)f2bf(v3.z),(short)f2bf(v3.w)};
      *(s16x8*)&At[srow][scol]     = o0;
      *(s16x8*)&At[srow][scol + 8] = o1;

      const float* s2 = Wp + (size_t)(cw0 + srow) * APP + k0 + scol;
      float4 u0 = *(const float4*)(s2);
      float4 u1 = *(const float4*)(s2 + 4);
      float4 u2 = *(const float4*)(s2 + 8);
      float4 u3 = *(const float4*)(s2 + 12);
      s16x8 p0 = {(short)f2bf(u0.x),(short)f2bf(u0.y),(short)f2bf(u0.z),(short)f2bf(u0.w),
                  (short)f2bf(u1.x),(short)f2bf(u1.y),(short)f2bf(u1.z),(short)f2bf(u1.w)};
      s16x8 p1 = {(short)f2bf(u2.x),(short)f2bf(u2.y),(short)f2bf(u2.z),(short)f2bf(u2.w),
                  (short)f2bf(u3.x),(short)f2bf(u3.y),(short)f2bf(u3.z),(short)f2bf(u3.w)};
      *(s16x8*)&Bt[srow][scol]     = p0;
      *(s16x8*)&Bt[srow][scol + 8] = p1;
    }
    __syncthreads();
    s16x8 af[4], bfv[4];
    #pragma unroll
    for (int i = 0; i < 4; ++i)
      af[i] = *(const s16x8*)&At[wr*64 + i*16 + c][g*8];
    #pragma unroll
    for (int i = 0; i < 4; ++i)
      bfv[i] = *(const s16x8*)&Bt[wc*64 + i*16 + c][g*8];
    #pragma unroll
    for (int mi = 0; mi < 4; ++mi)
      #pragma unroll
      for (int ni = 0; ni < 4; ++ni)
        acc[mi][ni] = __builtin_amdgcn_mfma_f32_16x16x32_bf16(af[mi], bfv[ni], acc[mi][ni], 0, 0, 0);
  }

  #pragma unroll
  for (int mi = 0; mi < 4; ++mi)
    #pragma unroll
    for (int ni = 0; ni < 4; ++ni)
      #pragma unroll
      for (int reg = 0; reg < 4; ++reg) {
        int m  = m0 + wr*64 + mi*16 + g*4 + reg;     // D row = (lane>>4)*4+reg
        int cl = cw0 + wc*64 + ni*16 + c;            // D col = lane&15
        float val = acc[mi][ni][reg] + bp[cl];
        int rr = cl / DKK, kk = cl % DKK;
        int bi = m >> 8, tt = m & 255;
        outp[(((size_t)rr*NB + bi)*NK + tt)*DKK + kk] = f2bf(val);
      }
}

// ---------------------------------------------------------------------------
// Kernel 2: geometric bias.  lb[b][m][n][r] = log(max(pos[b,m,n,:].WG_w[r]+WG_b[r], 1e-6))
// (relu then clip(1e-6) == max(.,1e-6)).  8 lanes cooperate per (m,n) pair:
// coalesced 3x float4 pos reads, shfl-xor reduce over the 8 lanes.
// ---------------------------------------------------------------------------
__global__ __launch_bounds__(256) void wg_kernel(
    const float* __restrict__ pos,
    const float* __restrict__ WGw, const float* __restrict__ WGb,
    u16* __restrict__ lb)
{
  __shared__ float wgs[8][96];
  __shared__ float wbs[8];
  const int t = threadIdx.x;
  for (int i = t; i < 768; i += 256) wgs[i / 96][i % 96] = WGw[i];
  if (t < 8) wbs[t] = WGb[t];
  __syncthreads();

  const int b = blockIdx.z, m0 = blockIdx.y * 32, n0 = blockIdx.x * 32;
  const int slot = t >> 3, l8 = t & 7;

  for (int i = 0; i < 32; ++i) {
    const float* p = pos + (((size_t)(b*NK + m0 + i) * NK) + n0 + slot) * 96 + l8 * 12;
    float4 q0 = *(const float4*)p;
    float4 q1 = *(const float4*)(p + 4);
    float4 q2 = *(const float4*)(p + 8);
    float pv[12] = {q0.x,q0.y,q0.z,q0.w, q1.x,q1.y,q1.z,q1.w, q2.x,q2.y,q2.z,q2.w};
    float acc[8] = {0.f,0.f,0.f,0.f,0.f,0.f,0.f,0.f};
    #pragma unroll
    for (int u = 0; u < 12; ++u) {
      float x = pv[u];
      int gi = l8 * 12 + u;
      #pragma unroll
      for (int rr = 0; rr < 8; ++rr) acc[rr] += x * wgs[rr][gi];
    }
    #pragma unroll
    for (int rr = 0; rr < 8; ++rr) {
      acc[rr] += __shfl_xor(acc[rr], 1);
      acc[rr] += __shfl_xor(acc[rr], 2);
      acc[rr] += __shfl_xor(acc[rr], 4);
    }
    if (l8 == 0) {
      s16x8 ov;
      #pragma unroll
      for (int rr = 0; rr < 8; ++rr)
        ov[rr] = (short)f2bf(logf(fmaxf(acc[rr] + wbs[rr], 1e-6f)));
      *(s16x8*)(lb + ((size_t)(b*NK + m0 + i) * NK + n0 + slot) * NR) = ov;
    }
  }
}

// ---------------------------------------------------------------------------
// Kernel 3: attention.  Per block: one (r,b) head, 128 query rows (n).
// Queries = n (softmax axis m becomes row-softmax). Two-pass: full S in regs
// (2x16 f32x4/lane), bias gathered from lb, softmax in regs via shfl over 16
// lanes, P~ -> LDS bf16, PV via MFMA with V staged transposed in LDS.
// ---------------------------------------------------------------------------
__global__ __launch_bounds__(256) void attn_kernel(
    const u16* __restrict__ wk, const u16* __restrict__ wq, const u16* __restrict__ wv,
    const u16* __restrict__ lb, const float* __restrict__ fa, float* __restrict__ out)
{
  __shared__ short Qs[128][104];     // 26.6 KB (rows 208B)
  __shared__ short Ks[32][104];      //  6.7 KB
  __shared__ short Ps[4][32][264];   // 67.6 KB (per-wave P~, rows 528B)
  __shared__ short VTs[96][264];     // 50.7 KB (V transposed [k][m])

  const int t = threadIdx.x;
  const int w = t >> 6, lane = t & 63;
  const int c = lane & 15, g = lane >> 4;
  const int n0 = blockIdx.x * 128;
  const int b = blockIdx.y;
  const int r = blockIdx.z;

  const size_t head = ((size_t)r * NB + b) * NK;
  const u16* Qg = wq + (head + n0) * DKK;
  const u16* Kg = wk + head * DKK;
  const u16* Vg = wv + head * DKK;

  { // stage Q: 128 x 96
    int row = t >> 1, q = t & 1;
    const u16* s = Qg + (size_t)row * DKK;
    #pragma unroll
    for (int j = 0; j < 6; ++j) {
      int col = (q + 2*j) * 8;
      *(s16x8*)&Qs[row][col] = *(const s16x8*)(s + col);
    }
  }
  { // stage V transposed: VTs[k][m]
    const u16* s = Vg + (size_t)t * DKK;
    #pragma unroll
    for (int j = 0; j < 12; ++j) {
      s16x8 v = *(const s16x8*)(s + j*8);
      #pragma unroll
      for (int u = 0; u < 8; ++u) VTs[j*8 + u][t] = v[u];
    }
  }

  f32x4 S[2][16];
  #pragma unroll
  for (int a = 0; a < 2; ++a)
    #pragma unroll
    for (int q = 0; q < 16; ++q)
      S[a][q] = (f32x4){0.f, 0.f, 0.f, 0.f};

  const float scale = 0.10206207261596575f;  // 1/sqrt(96)

  #pragma unroll
  for (int ms = 0; ms < 8; ++ms) {
    __syncthreads();
    if (t < 128) { // stage K rows ms*32..+32
      int row = t >> 2, q = t & 3;
      const u16* s = Kg + (size_t)(ms*32 + row) * DKK;
      #pragma unroll
      for (int j = 0; j < 3; ++j) {
        int col = q*8 + j*32;
        *(s16x8*)&Ks[row][col] = *(const s16x8*)(s + col);
      }
    }
    __syncthreads();
    #pragma unroll
    for (int mj = 0; mj < 2; ++mj) {
      f32x4 sa[2] = {(f32x4){0.f,0.f,0.f,0.f}, (f32x4){0.f,0.f,0.f,0.f}};
      #pragma unroll
      for (int kc = 0; kc < 3; ++kc) {
        s16x8 bv = *(const s16x8*)&Ks[mj*16 + c][kc*32 + g*8];
        s16x8 a0 = *(const s16x8*)&Qs[w*32 + c][kc*32 + g*8];
        s16x8 a1 = *(const s16x8*)&Qs[w*32 + 16 + c][kc*32 + g*8];
        sa[0] = __builtin_amdgcn_mfma_f32_16x16x32_bf16(a0, bv, sa[0], 0, 0, 0);
        sa[1] = __builtin_amdgcn_mfma_f32_16x16x32_bf16(a1, bv, sa[1], 0, 0, 0);
      }
      const int mglob = ms*32 + mj*16 + c;   // S col = lane&15
      const u16* bb = lb + ((size_t)(b*NK + mglob) * NK) * NR + r;
      #pragma unroll
      for (int ni = 0; ni < 2; ++ni)
        #pragma unroll
        for (int reg = 0; reg < 4; ++reg) {
          int nglob = n0 + w*32 + ni*16 + g*4 + reg;  // S row
          float bias = bf2f(bb[(size_t)nglob * NR]);
          S[ni][ms*2 + mj][reg] = sa[ni][reg] * scale + bias;
        }
    }
  }

  // softmax over m (within-lane 16 + shfl over the 16 c-lanes)
  float rsum[2][4];
  #pragma unroll
  for (int ni = 0; ni < 2; ++ni)
    #pragma unroll
    for (int reg = 0; reg < 4; ++reg) {
      float mx = -3e38f;
      #pragma unroll
      for (int mi = 0; mi < 16; ++mi) mx = fmaxf(mx, S[ni][mi][reg]);
      mx = fmaxf(mx, __shfl_xor(mx, 1));
      mx = fmaxf(mx, __shfl_xor(mx, 2));
      mx = fmaxf(mx, __shfl_xor(mx, 4));
      mx = fmaxf(mx, __shfl_xor(mx, 8));
      float sm = 0.f;
      #pragma unroll
      for (int mi = 0; mi < 16; ++mi) {
        float p = __expf(S[ni][mi][reg] - mx);
        S[ni][mi][reg] = p;
        sm += p;
      }
      sm += __shfl_xor(sm, 1);
      sm += __shfl_xor(sm, 2);
      sm += __shfl_xor(sm, 4);
      sm += __shfl_xor(sm, 8);
      rsum[ni][reg] = sm;
    }

  // write P~ (bf16, unnormalized) to this wave's LDS region
  #pragma unroll
  for (int ni = 0; ni < 2; ++ni)
    #pragma unroll
    for (int mi = 0; mi < 16; ++mi)
      #pragma unroll
      for (int reg = 0; reg < 4; ++reg)
        Ps[w][ni*16 + g*4 + reg][mi*16 + c] = (short)f2bf(S[ni][mi][reg]);

  __syncthreads();

  // PV: out[n][k] = sum_m P~[n][m] * V[m][k]
  f32x4 o[2][6];
  #pragma unroll
  for (int a = 0; a < 2; ++a)
    #pragma unroll
    for (int q = 0; q < 6; ++q)
      o[a][q] = (f32x4){0.f, 0.f, 0.f, 0.f};

  #pragma unroll
  for (int mc = 0; mc < 8; ++mc) {
    s16x8 a0 = *(const s16x8*)&Ps[w][c][mc*32 + g*8];
    s16x8 a1 = *(const s16x8*)&Ps[w][16 + c][mc*32 + g*8];
    #pragma unroll
    for (int ki = 0; ki < 6; ++ki) {
      s16x8 bv = *(const s16x8*)&VTs[ki*16 + c][mc*32 + g*8];
      o[0][ki] = __builtin_amdgcn_mfma_f32_16x16x32_bf16(a0, bv, o[0][ki], 0, 0, 0);
      o[1][ki] = __builtin_amdgcn_mfma_f32_16x16x32_bf16(a1, bv, o[1][ki], 0, 0, 0);
    }
  }

  // epilogue: normalize, residual add, store fp32
  #pragma unroll
  for (int ni = 0; ni < 2; ++ni)
    #pragma unroll
    for (int ki = 0; ki < 6; ++ki)
      #pragma unroll
      for (int reg = 0; reg < 4; ++reg) {
        int nglob = n0 + w*32 + ni*16 + g*4 + reg;
        int d = r*DKK + ki*16 + c;
        size_t adr = ((size_t)b*NK + nglob) * (NR*DKK) + d;
        out[adr] = o[ni][ki][reg] / rsum[ni][reg] + fa[adr];
      }
}

extern "C" void kernel_launch(void* const* d_in, const int* in_sizes, int n_in,
                              void* d_out, int out_size, void* d_ws, size_t ws_size,
                              hipStream_t stream) {
  (void)in_sizes; (void)n_in; (void)out_size;
  const float* fa  = (const float*)d_in[0];
  const float* pos = (const float*)d_in[1];
  const float* WGw = (const float*)d_in[2];
  const float* WGb = (const float*)d_in[3];
  const float* WKw = (const float*)d_in[4];
  const float* WKb = (const float*)d_in[5];
  const float* WQw = (const float*)d_in[6];
  const float* WQb = (const float*)d_in[7];
  const float* WVw = (const float*)d_in[8];
  const float* WVb = (const float*)d_in[9];
  float* outp = (float*)d_out;

  // workspace: 3 x 6.29MB bf16 K/Q/V + 16.8MB bf16 log-bias = 35.7 MB
  const size_t kqv = (size_t)NR * NB * NK * DKK;
  u16* wk = (u16*)d_ws;
  u16* wq = wk + kqv;
  u16* wv = wq + kqv;
  u16* lb = wv + kqv;
  (void)ws_size;

  hipLaunchKernelGGL(proj_kernel, dim3(32, 18), dim3(256), 0, stream,
                     fa, WKw, WKb, WQw, WQb, WVw, WVb, wk, wq, wv);
  hipLaunchKernelGGL(wg_kernel, dim3(8, 8, 16), dim3(256), 0, stream,
                     pos, WGw, WGb, lb);
  hipLaunchKernelGGL(attn_kernel, dim3(2, NB, NR), dim3(256), 0, stream,
                     wk, wq, wv, lb, fa, outp);
}

// Round 2
// 194.769 us; speedup vs baseline: 1.0912x; 1.0912x over previous
//
#include <hip/hip_runtime.h>
#include <hip/hip_bf16.h>

typedef __attribute__((ext_vector_type(8))) short s16x8;
typedef __attribute__((ext_vector_type(4))) float f32x4;
typedef unsigned short u16;

#define NB 16
#define NK 256
#define APP 768
#define DKK 96
#define NR 8
#define QSCALE 0.10206207261596575f   // 1/sqrt(96), folded into Q at projection

__device__ __forceinline__ u16 f2bf(float f) {
  union { float f; unsigned int u; } v; v.f = f;
  unsigned int x = v.u;
  x += 0x7fffu + ((x >> 16) & 1u);
  return (u16)(x >> 16);
}
__device__ __forceinline__ float bf2f(u16 h) {
  union { unsigned int u; float f; } v; v.u = ((unsigned int)h) << 16;
  return v.f;
}
__device__ __forceinline__ void gload_lds16(const void* g, void* l) {
  __builtin_amdgcn_global_load_lds(
      (const __attribute__((address_space(1))) unsigned int*)g,
      (__attribute__((address_space(3))) unsigned int*)l, 16, 0, 0);
}

// ---------------------------------------------------------------------------
// Kernel 0: convert f_a and the 3 projection weights to bf16.
// fab: [4096][768] bf16;  Wb: [2304][768] bf16 (WK rows 0-767, WQ, WV).
// ---------------------------------------------------------------------------
__global__ __launch_bounds__(256) void conv_kernel(
    const float* __restrict__ fa,
    const float* __restrict__ WKw, const float* __restrict__ WQw,
    const float* __restrict__ WVw,
    u16* __restrict__ fab, u16* __restrict__ Wb)
{
  const int idx = blockIdx.x * 256 + threadIdx.x;
  const int faCh = NB * NK * APP / 8;      // 393216
  const int wCh  = NR * DKK * APP / 8;     // 73728 per weight array
  const float* src; u16* dst;
  if (idx < faCh) {
    src = fa + (size_t)idx * 8;
    dst = fab + (size_t)idx * 8;
  } else {
    int o = idx - faCh;
    int a = o / wCh;
    int oo = o - a * wCh;
    const float* wsrc = a == 0 ? WKw : (a == 1 ? WQw : WVw);
    src = wsrc + (size_t)oo * 8;
    dst = Wb + (size_t)a * (NR * DKK * APP) + (size_t)oo * 8;
  }
  float4 v0 = *(const float4*)src;
  float4 v1 = *(const float4*)(src + 4);
  s16x8 ov = {(short)f2bf(v0.x),(short)f2bf(v0.y),(short)f2bf(v0.z),(short)f2bf(v0.w),
              (short)f2bf(v1.x),(short)f2bf(v1.y),(short)f2bf(v1.z),(short)f2bf(v1.w)};
  *(s16x8*)dst = ov;
}

// ---------------------------------------------------------------------------
// Kernel 1: projections (bf16 GEMM, m97 structure).
// C[m,c] = fab[m,:].Wb[c,:] + bias.  128x128 tile, BK=64, 4 waves (64x64 each).
// global_load_lds width=16 with both-sides XOR swizzle:
//   LDS chunk (row*8+x) holds global col-group x^(row&7); reads XOR the same.
// Outputs: wk,wq row-major [r][b][m][k] (Q pre-scaled by 1/sqrt(96));
//          wvT transposed [r][b][k][m] for the attention PV B-operand.
// ---------------------------------------------------------------------------
__global__ __launch_bounds__(256) void proj_kernel(
    const u16* __restrict__ fab, const u16* __restrict__ Wb,
    const float* __restrict__ WKb, const float* __restrict__ WQb,
    const float* __restrict__ WVb,
    u16* __restrict__ wk, u16* __restrict__ wq, u16* __restrict__ wvT)
{
  __shared__ u16 As[128 * 64];   // 16 KB, linear (gld_lds dest), swizzled content
  __shared__ u16 Bs[128 * 64];   // 16 KB
  const int t = threadIdx.x;
  const int lane = t & 63, w = t >> 6;
  const int c = lane & 15, g = lane >> 4;
  const int wr = w >> 1, wc = w & 1;
  const int m0 = blockIdx.x * 128;
  const int c0 = blockIdx.y * 128;

  f32x4 acc[4][4] = {};

  for (int k0 = 0; k0 < APP; k0 += 64) {
    __syncthreads();
    #pragma unroll
    for (int i = 0; i < 4; ++i) {
      int n = t + i * 256;               // chunk id, 0..1023
      int row = n >> 3, cg = n & 7;
      int scg = cg ^ (row & 7);          // pre-swizzled global col-group
      gload_lds16(fab + (size_t)(m0 + row) * APP + k0 + scg * 8, As + n * 8);
      gload_lds16(Wb  + (size_t)(c0 + row) * APP + k0 + scg * 8, Bs + n * 8);
    }
    __syncthreads();
    #pragma unroll
    for (int kc = 0; kc < 2; ++kc) {
      s16x8 af[4], bfr[4];
      #pragma unroll
      for (int i = 0; i < 4; ++i) {
        int arow = wr * 64 + i * 16 + c;
        af[i]  = *(const s16x8*)(As + (((arow << 3) | ((kc * 4 + g) ^ (arow & 7))) << 3));
        int brow = wc * 64 + i * 16 + c;
        bfr[i] = *(const s16x8*)(Bs + (((brow << 3) | ((kc * 4 + g) ^ (brow & 7))) << 3));
      }
      #pragma unroll
      for (int mi = 0; mi < 4; ++mi)
        #pragma unroll
        for (int ni = 0; ni < 4; ++ni)
          acc[mi][ni] = __builtin_amdgcn_mfma_f32_16x16x32_bf16(af[mi], bfr[ni], acc[mi][ni], 0, 0, 0);
    }
  }

  const int arr = blockIdx.y / 6;            // 0=K 1=Q 2=V (tiles never straddle)
  const int cw0 = c0 - arr * APP;
  const float* bp = arr == 0 ? WKb : (arr == 1 ? WQb : WVb);

  #pragma unroll
  for (int mi = 0; mi < 4; ++mi)
    #pragma unroll
    for (int ni = 0; ni < 4; ++ni) {
      int clw = cw0 + wc * 64 + ni * 16 + c;
      float bias = bp[clw];
      int rr = clw / DKK, kk = clw - rr * DKK;
      #pragma unroll
      for (int e = 0; e < 4; ++e) {
        int m = m0 + wr * 64 + mi * 16 + g * 4 + e;   // D row=(lane>>4)*4+e
        float val = acc[mi][ni][e] + bias;
        if (arr == 1) val *= QSCALE;
        int bi = m >> 8, tt = m & 255;
        if (arr == 2)
          wvT[(((size_t)rr * NB + bi) * DKK + kk) * NK + tt] = f2bf(val);
        else {
          u16* op = arr == 0 ? wk : wq;
          op[(((size_t)rr * NB + bi) * NK + tt) * DKK + kk] = f2bf(val);
        }
      }
    }
}

// ---------------------------------------------------------------------------
// Kernel 2: geometric bias.  lb2[r][b][m][n] = log(max(pos[b,m,n,:].WGw[r]+WGb[r],1e-6))
// n innermost so attention can read b64 runs.  8 lanes cooperate per (m,n);
// after butterfly every lane has all 8 sums; lane l8 stores plane r=l8.
// ---------------------------------------------------------------------------
__global__ __launch_bounds__(256) void wg_kernel(
    const float* __restrict__ pos,
    const float* __restrict__ WGw, const float* __restrict__ WGb,
    u16* __restrict__ lb2)
{
  __shared__ float wgs[8][96];
  __shared__ float wbs[8];
  const int t = threadIdx.x;
  for (int i = t; i < 768; i += 256) wgs[i / 96][i % 96] = WGw[i];
  if (t < 8) wbs[t] = WGb[t];
  __syncthreads();

  const int b = blockIdx.z, m0 = blockIdx.y * 32, n0 = blockIdx.x * 32;
  const int slot = t >> 3, l8 = t & 7;

  for (int i = 0; i < 32; ++i) {
    const float* p = pos + (((size_t)(b * NK + m0 + i) * NK) + n0 + slot) * 96 + l8 * 12;
    float4 q0 = *(const float4*)p;
    float4 q1 = *(const float4*)(p + 4);
    float4 q2 = *(const float4*)(p + 8);
    float pv[12] = {q0.x,q0.y,q0.z,q0.w, q1.x,q1.y,q1.z,q1.w, q2.x,q2.y,q2.z,q2.w};
    float acc[8] = {0.f,0.f,0.f,0.f,0.f,0.f,0.f,0.f};
    #pragma unroll
    for (int u = 0; u < 12; ++u) {
      float x = pv[u];
      int gi = l8 * 12 + u;
      #pragma unroll
      for (int rr = 0; rr < 8; ++rr) acc[rr] += x * wgs[rr][gi];
    }
    #pragma unroll
    for (int rr = 0; rr < 8; ++rr) {
      acc[rr] += __shfl_xor(acc[rr], 1);
      acc[rr] += __shfl_xor(acc[rr], 2);
      acc[rr] += __shfl_xor(acc[rr], 4);
    }
    // static select tree (no dynamic register indexing -> no scratch)
    float v = l8 < 4 ? (l8 < 2 ? (l8 == 0 ? acc[0] : acc[1])
                               : (l8 == 2 ? acc[2] : acc[3]))
                     : (l8 < 6 ? (l8 == 4 ? acc[4] : acc[5])
                               : (l8 == 6 ? acc[6] : acc[7]));
    v = __logf(fmaxf(v + wbs[l8], 1e-6f));
    lb2[(((size_t)l8 * NB + b) * NK + m0 + i) * NK + n0 + slot] = f2bf(v);
  }
}

// ---------------------------------------------------------------------------
// Kernel 3: attention.  512 blocks (4 n-blocks x 16 b x 8 r), 4 waves each,
// wave owns 16 query rows (n).  No staging LDS, zero __syncthreads:
//  - Q/K fragments read directly from wq/wk (L2/L3-resident bf16)
//  - bias b64 loaded straight into the MFMA C operand
//  - full S row (256 m) in 16 f32x4 regs; softmax via in-lane + shfl over c
//  - P chunks through a tiny per-wave LDS buffer; V^T fragments from wvT
// ---------------------------------------------------------------------------
__global__ __launch_bounds__(256) void attn_kernel(
    const u16* __restrict__ wk, const u16* __restrict__ wq,
    const u16* __restrict__ wvT, const u16* __restrict__ lb2,
    const float* __restrict__ fa, float* __restrict__ out)
{
  __shared__ u16 Ps[4][16][40];   // per-wave P chunk [16 n][32 m], 80B rows
  const int t = threadIdx.x;
  const int w = t >> 6, lane = t & 63;
  const int c = lane & 15, g = lane >> 4;
  const int b = blockIdx.y, r = blockIdx.z;
  const int nb = blockIdx.x * 64 + w * 16;

  const size_t hb = (size_t)r * NB + b;
  const u16* Qr = wq + (hb * NK + nb + c) * DKK + g * 8;
  const u16* Kr = wk + (hb * NK + c) * DKK + g * 8;
  const u16* Vr = wvT + (hb * DKK + c) * NK + g * 8;
  const u16* Br = lb2 + hb * NK * NK + (size_t)c * NK + nb + g * 4;

  s16x8 qf[3];
  #pragma unroll
  for (int kc = 0; kc < 3; ++kc) qf[kc] = *(const s16x8*)(Qr + kc * 32);

  // S[n = nb+g*4+e][m = mt*16+c], Q pre-scaled, bias as MFMA C-input
  f32x4 S[16];
  #pragma unroll
  for (int mt = 0; mt < 16; ++mt) {
    ushort4 bb = *(const ushort4*)(Br + (size_t)mt * 16 * NK);
    f32x4 sa = {bf2f(bb.x), bf2f(bb.y), bf2f(bb.z), bf2f(bb.w)};
    #pragma unroll
    for (int kc = 0; kc < 3; ++kc) {
      s16x8 kf = *(const s16x8*)(Kr + (size_t)mt * 16 * DKK + kc * 32);
      sa = __builtin_amdgcn_mfma_f32_16x16x32_bf16(qf[kc], kf, sa, 0, 0, 0);
    }
    S[mt] = sa;
  }

  // softmax over m: 16 in-lane + shfl_xor over the 16 c-lanes
  float rinv[4];
  #pragma unroll
  for (int e = 0; e < 4; ++e) {
    float mx = S[0][e];
    #pragma unroll
    for (int mt = 1; mt < 16; ++mt) mx = fmaxf(mx, S[mt][e]);
    mx = fmaxf(mx, __shfl_xor(mx, 1));
    mx = fmaxf(mx, __shfl_xor(mx, 2));
    mx = fmaxf(mx, __shfl_xor(mx, 4));
    mx = fmaxf(mx, __shfl_xor(mx, 8));
    float sm = 0.f;
    #pragma unroll
    for (int mt = 0; mt < 16; ++mt) {
      float p = __expf(S[mt][e] - mx);
      S[mt][e] = p;
      sm += p;
    }
    sm += __shfl_xor(sm, 1);
    sm += __shfl_xor(sm, 2);
    sm += __shfl_xor(sm, 4);
    sm += __shfl_xor(sm, 8);
    rinv[e] = 1.f / sm;
  }

  // PV in 8 chunks of 32 m: stage P chunk (per-wave LDS), MFMA vs wvT frags
  f32x4 o[6];
  #pragma unroll
  for (int ki = 0; ki < 6; ++ki) o[ki] = (f32x4){0.f, 0.f, 0.f, 0.f};

  #pragma unroll
  for (int mc = 0; mc < 8; ++mc) {
    #pragma unroll
    for (int e = 0; e < 4; ++e) {
      Ps[w][g * 4 + e][c]      = f2bf(S[2 * mc][e]);
      Ps[w][g * 4 + e][16 + c] = f2bf(S[2 * mc + 1][e]);
    }
    s16x8 pa = *(const s16x8*)&Ps[w][c][g * 8];
    #pragma unroll
    for (int ki = 0; ki < 6; ++ki) {
      s16x8 vf = *(const s16x8*)(Vr + (size_t)(ki * 16) * NK + mc * 32);
      o[ki] = __builtin_amdgcn_mfma_f32_16x16x32_bf16(pa, vf, o[ki], 0, 0, 0);
    }
  }

  // epilogue: normalize, residual, fp32 store (lanes c -> 64B coalesced runs)
  #pragma unroll
  for (int ki = 0; ki < 6; ++ki)
    #pragma unroll
    for (int e = 0; e < 4; ++e) {
      int n = nb + g * 4 + e;
      size_t adr = ((size_t)b * NK + n) * (NR * DKK) + r * DKK + ki * 16 + c;
      out[adr] = o[ki][e] * rinv[e] + fa[adr];
    }
}

extern "C" void kernel_launch(void* const* d_in, const int* in_sizes, int n_in,
                              void* d_out, int out_size, void* d_ws, size_t ws_size,
                              hipStream_t stream) {
  (void)in_sizes; (void)n_in; (void)out_size; (void)ws_size;
  const float* fa  = (const float*)d_in[0];
  const float* pos = (const float*)d_in[1];
  const float* WGw = (const float*)d_in[2];
  const float* WGb = (const float*)d_in[3];
  const float* WKw = (const float*)d_in[4];
  const float* WKb = (const float*)d_in[5];
  const float* WQw = (const float*)d_in[6];
  const float* WQb = (const float*)d_in[7];
  const float* WVw = (const float*)d_in[8];
  const float* WVb = (const float*)d_in[9];
  float* outp = (float*)d_out;

  // workspace: fab 6.3MB + Wb 3.5MB + wk/wq/wvT 18.9MB + lb2 16.8MB = 45.5MB
  const size_t faN = (size_t)NB * NK * APP;       // 3,145,728
  const size_t wN  = (size_t)3 * NR * DKK * APP;  // 1,769,472
  const size_t kqv = (size_t)NR * NB * NK * DKK;  // 3,145,728
  u16* fab = (u16*)d_ws;
  u16* Wb  = fab + faN;
  u16* wk  = Wb + wN;
  u16* wq  = wk + kqv;
  u16* wvT = wq + kqv;
  u16* lb2 = wvT + kqv;

  hipLaunchKernelGGL(conv_kernel, dim3(2400), dim3(256), 0, stream,
                     fa, WKw, WQw, WVw, fab, Wb);
  hipLaunchKernelGGL(proj_kernel, dim3(32, 18), dim3(256), 0, stream,
                     fab, Wb, WKb, WQb, WVb, wk, wq, wvT);
  hipLaunchKernelGGL(wg_kernel, dim3(8, 8, 16), dim3(256), 0, stream,
                     pos, WGw, WGb, lb2);
  hipLaunchKernelGGL(attn_kernel, dim3(4, NB, NR), dim3(256), 0, stream,
                     wk, wq, wvT, lb2, fa, outp);
}